// Round 1
// baseline (127.667 us; speedup 1.0000x reference)
//
#include <hip/hip_runtime.h>
#include <hip/hip_bf16.h>

#define D_MODEL 1024
#define D_STATE 16
#define BATCH   4
#define SEQ     2048
#define ROWS    (BATCH*SEQ)   // 8192
#define WIN     64            // FIR window; decay<=0.55 => decay^64 < 1e-16

// ---------------------------------------------------------------------------
// K1: bx[row][n] = sum_d x[row][d] * B_w[n][d]     (row = b*SEQ + t)
// Block: 256 threads = 16 dblk x 16 n, handles 8 rows. x staged in LDS
// (pad 1028 to vary banks per row), B_w slice (64 floats) held in VGPRs.
// ---------------------------------------------------------------------------
#define K1_ROWS 8
__global__ __launch_bounds__(256) void k_bx(const float* __restrict__ x,
                                            const float* __restrict__ Bw,
                                            float* __restrict__ bx) {
    __shared__ float xs[K1_ROWS][1028];
    __shared__ float red[4][16];
    const int tid  = threadIdx.x;
    const int n    = tid & 15;
    const int dblk = tid >> 4;              // 0..15, covers d = dblk*64 .. +63
    const int row0 = blockIdx.x * K1_ROWS;
    const int lane = tid & 63, wid = tid >> 6;

    // preload B_w[n][dblk*64 .. +63] into 16 float4 (64 VGPRs)
    float4 bw[16];
    const float4* bwp = reinterpret_cast<const float4*>(Bw + n * 1024 + dblk * 64);
#pragma unroll
    for (int j = 0; j < 16; ++j) bw[j] = bwp[j];

    // stage 8 rows of x (coalesced float4)
#pragma unroll
    for (int r = 0; r < K1_ROWS; ++r) {
        float4 v = reinterpret_cast<const float4*>(x + (size_t)(row0 + r) * 1024)[tid];
        *reinterpret_cast<float4*>(&xs[r][tid * 4]) = v;
    }
    __syncthreads();

    for (int r = 0; r < K1_ROWS; ++r) {
        float s = 0.f;
#pragma unroll
        for (int jj = 0; jj < 16; ++jj) {
            int j = (jj + dblk) & 15;       // stagger start -> conflict-free banks
            float4 xv = *reinterpret_cast<const float4*>(&xs[r][dblk * 64 + j * 4]);
            float4 b  = bw[j];
            s = fmaf(xv.x, b.x, s); s = fmaf(xv.y, b.y, s);
            s = fmaf(xv.z, b.z, s); s = fmaf(xv.w, b.w, s);
        }
        // reduce over dblk: xor16/xor32 fold the wave's 4 dblks per n
        s += __shfl_xor(s, 16);
        s += __shfl_xor(s, 32);
        if (lane < 16) red[wid][lane] = s;
        __syncthreads();
        if (tid < 16) {
            float v = red[0][tid] + red[1][tid] + red[2][tid] + red[3][tid];
            bx[(size_t)(row0 + r) * D_STATE + tid] = v;
        }
        __syncthreads();
    }
}

// ---------------------------------------------------------------------------
// K2: KbarT[delta][n] = (1/1024) * sum_d decay[d][n]^delta,  decay=exp(-exp(A))
// Grid: 16 blocks (one per n) x 256 threads (4 d each).
// ---------------------------------------------------------------------------
__global__ __launch_bounds__(256) void k_kbar(const float* __restrict__ A_log,
                                              float* __restrict__ KbarT) {
    const int n = blockIdx.x;
    const int tid = threadIdx.x;
    const int lane = tid & 63, wid = tid >> 6;
    __shared__ float red[4];
    float p[4], dec[4];
#pragma unroll
    for (int j = 0; j < 4; ++j) {
        int d = tid * 4 + j;
        float a = A_log[d * D_STATE + n];
        dec[j] = expf(-expf(a));
        p[j] = 1.f;
    }
    for (int delta = 0; delta < WIN; ++delta) {
        float s = p[0] + p[1] + p[2] + p[3];
#pragma unroll
        for (int off = 32; off; off >>= 1) s += __shfl_xor(s, off);
        if (lane == 0) red[wid] = s;
        __syncthreads();
        if (tid == 0)
            KbarT[delta * D_STATE + n] = (red[0] + red[1] + red[2] + red[3]) * (1.0f / 1024.0f);
        __syncthreads();
#pragma unroll
        for (int j = 0; j < 4; ++j) p[j] *= dec[j];
    }
}

// ---------------------------------------------------------------------------
// K3: hm[row][n] = sum_{delta<min(t+1,WIN)} KbarT[delta][n] * bx[row-delta][n]
// One thread per (row,n). Kbar staged in LDS ([delta][n] layout: conflict-free).
// ---------------------------------------------------------------------------
__global__ __launch_bounds__(256) void k_fir(const float* __restrict__ bx,
                                             const float* __restrict__ KbarT,
                                             float* __restrict__ hm) {
    __shared__ float kb[WIN * D_STATE];
    const int tid = threadIdx.x;
    for (int i = tid; i < WIN * D_STATE; i += 256) kb[i] = KbarT[i];
    __syncthreads();

    const int gid = blockIdx.x * 256 + tid;       // row*16 + n
    const int n   = gid & 15;
    const int row = gid >> 4;
    const int t   = row & (SEQ - 1);
    const float* bp = bx + (size_t)row * D_STATE + n;
    float acc = 0.f;
    if (t >= WIN - 1) {
#pragma unroll
        for (int delta = 0; delta < WIN; ++delta)
            acc = fmaf(kb[delta * D_STATE + n], bp[-(ptrdiff_t)delta * D_STATE], acc);
    } else {
        int kw = t + 1;
        for (int delta = 0; delta < kw; ++delta)
            acc = fmaf(kb[delta * D_STATE + n], bp[-(ptrdiff_t)delta * D_STATE], acc);
    }
    hm[gid] = acc;
}

// ---------------------------------------------------------------------------
// K4: y = hm @ C_w^T + D*x ; out = layernorm(y)*gamma + beta
// Block: 256 threads, 8 rows; thread owns d = 4*tid..+3, C_w slice in VGPRs.
// ---------------------------------------------------------------------------
#define K4_ROWS 8
__global__ __launch_bounds__(256) void k_out(const float* __restrict__ x,
                                             const float* __restrict__ hm,
                                             const float* __restrict__ Cw,
                                             const float* __restrict__ Dp,
                                             const float* __restrict__ gamma,
                                             const float* __restrict__ beta,
                                             float* __restrict__ out) {
    const int tid = threadIdx.x;
    const int row0 = blockIdx.x * K4_ROWS;
    const int lane = tid & 63, wid = tid >> 6;
    __shared__ float red_s[4], red_q[4];

    // preload C_w rows d = 4*tid..+3 (16 floats each) -> 64 VGPRs
    float4 cw[4][4];
#pragma unroll
    for (int j = 0; j < 4; ++j) {
        const float4* p = reinterpret_cast<const float4*>(Cw + (size_t)(tid * 4 + j) * D_STATE);
#pragma unroll
        for (int q = 0; q < 4; ++q) cw[j][q] = p[q];
    }
    const float4 Dv = reinterpret_cast<const float4*>(Dp)[tid];
    const float4 gv = reinterpret_cast<const float4*>(gamma)[tid];
    const float4 bv = reinterpret_cast<const float4*>(beta)[tid];

    for (int r = 0; r < K4_ROWS; ++r) {
        const size_t row = row0 + r;
        const float4* hmp = reinterpret_cast<const float4*>(hm + row * D_STATE);
        float4 h0 = hmp[0], h1 = hmp[1], h2 = hmp[2], h3 = hmp[3];
        float4 xv = reinterpret_cast<const float4*>(x + row * 1024)[tid];

        float y[4];
#pragma unroll
        for (int j = 0; j < 4; ++j) {
            float a = 0.f;
            a = fmaf(h0.x, cw[j][0].x, a); a = fmaf(h0.y, cw[j][0].y, a);
            a = fmaf(h0.z, cw[j][0].z, a); a = fmaf(h0.w, cw[j][0].w, a);
            a = fmaf(h1.x, cw[j][1].x, a); a = fmaf(h1.y, cw[j][1].y, a);
            a = fmaf(h1.z, cw[j][1].z, a); a = fmaf(h1.w, cw[j][1].w, a);
            a = fmaf(h2.x, cw[j][2].x, a); a = fmaf(h2.y, cw[j][2].y, a);
            a = fmaf(h2.z, cw[j][2].z, a); a = fmaf(h2.w, cw[j][2].w, a);
            a = fmaf(h3.x, cw[j][3].x, a); a = fmaf(h3.y, cw[j][3].y, a);
            a = fmaf(h3.z, cw[j][3].z, a); a = fmaf(h3.w, cw[j][3].w, a);
            y[j] = a;
        }
        y[0] = fmaf(Dv.x, xv.x, y[0]);
        y[1] = fmaf(Dv.y, xv.y, y[1]);
        y[2] = fmaf(Dv.z, xv.z, y[2]);
        y[3] = fmaf(Dv.w, xv.w, y[3]);

        float s  = y[0] + y[1] + y[2] + y[3];
        float sq = y[0]*y[0] + y[1]*y[1] + y[2]*y[2] + y[3]*y[3];
#pragma unroll
        for (int off = 32; off; off >>= 1) {
            s  += __shfl_xor(s,  off);
            sq += __shfl_xor(sq, off);
        }
        if (lane == 0) { red_s[wid] = s; red_q[wid] = sq; }
        __syncthreads();
        float ssum = red_s[0] + red_s[1] + red_s[2] + red_s[3];
        float ssq  = red_q[0] + red_q[1] + red_q[2] + red_q[3];
        float mu   = ssum * (1.0f / 1024.0f);
        float var  = ssq * (1.0f / 1024.0f) - mu * mu;
        float inv  = rsqrtf(var + 1e-5f);
        float4 o;
        o.x = fmaf((y[0] - mu) * inv, gv.x, bv.x);
        o.y = fmaf((y[1] - mu) * inv, gv.y, bv.y);
        o.z = fmaf((y[2] - mu) * inv, gv.z, bv.z);
        o.w = fmaf((y[3] - mu) * inv, gv.w, bv.w);
        reinterpret_cast<float4*>(out + row * 1024)[tid] = o;
        __syncthreads();   // protect red_* before next row
    }
}

extern "C" void kernel_launch(void* const* d_in, const int* in_sizes, int n_in,
                              void* d_out, int out_size, void* d_ws, size_t ws_size,
                              hipStream_t stream) {
    (void)in_sizes; (void)n_in; (void)out_size; (void)ws_size;
    const float* x     = (const float*)d_in[0];
    const float* A_log = (const float*)d_in[1];
    const float* B_w   = (const float*)d_in[2];
    const float* C_w   = (const float*)d_in[3];
    const float* Dp    = (const float*)d_in[4];
    const float* gamma = (const float*)d_in[5];
    const float* beta  = (const float*)d_in[6];
    float* out = (float*)d_out;

    float* bx = (float*)d_ws;                       // ROWS*16 floats (512 KB)
    float* hm = bx + (size_t)ROWS * D_STATE;        // ROWS*16 floats (512 KB)
    float* kb = hm + (size_t)ROWS * D_STATE;        // WIN*16 floats (4 KB)

    k_bx  <<<ROWS / K1_ROWS, 256, 0, stream>>>(x, B_w, bx);
    k_kbar<<<D_STATE,        256, 0, stream>>>(A_log, kb);
    k_fir <<<ROWS * D_STATE / 256, 256, 0, stream>>>(bx, kb, hm);
    k_out <<<ROWS / K4_ROWS, 256, 0, stream>>>(x, hm, C_w, Dp, gamma, beta, out);
}

// Round 2
// 77.230 us; speedup vs baseline: 1.6531x; 1.6531x over previous
//
#include <hip/hip_runtime.h>
#include <hip/hip_bf16.h>

#define D_MODEL 1024
#define D_STATE 16
#define BATCH   4
#define SEQ     2048
#define ROWS    (BATCH*SEQ)   // 8192
#define WIN     64            // FIR window; decay<=0.55 => decay^64 < 1e-16

// ---------------------------------------------------------------------------
// K1: bx[row][n] = sum_d x[row][d] * B_w[n][d]     (row = b*SEQ + t)
// Block: 256 threads = 16 dblk x 16 n, handles 8 rows. x staged in LDS.
// B_w slice (16 float4) pre-rotated by dblk at LOAD time so the inner loop
// indexes bw[] with a COMPILE-TIME index (rule #20: runtime-indexed register
// arrays spill to scratch -- that was R0's 66 MB WRITE_SIZE).
// ---------------------------------------------------------------------------
#define K1_ROWS 8
__global__ __launch_bounds__(256) void k_bx(const float* __restrict__ x,
                                            const float* __restrict__ Bw,
                                            float* __restrict__ bx) {
    __shared__ float xs[K1_ROWS][1024];
    __shared__ float red[4][K1_ROWS][16];
    const int tid  = threadIdx.x;
    const int n    = tid & 15;
    const int dblk = tid >> 4;              // 0..15, covers d = dblk*64 .. +63
    const int row0 = blockIdx.x * K1_ROWS;
    const int lane = tid & 63, wid = tid >> 6;

    // preload B_w[n][dblk*64 .. +63], rotated by dblk (bank-stagger at load)
    float4 bw[16];
    const float4* bwp = reinterpret_cast<const float4*>(Bw + n * 1024 + dblk * 64);
#pragma unroll
    for (int jj = 0; jj < 16; ++jj) bw[jj] = bwp[(jj + dblk) & 15];

    // stage 8 rows of x (coalesced float4)
#pragma unroll
    for (int r = 0; r < K1_ROWS; ++r) {
        float4 v = reinterpret_cast<const float4*>(x + (size_t)(row0 + r) * 1024)[tid];
        *reinterpret_cast<float4*>(&xs[r][tid * 4]) = v;
    }
    __syncthreads();

    float s[K1_ROWS];
#pragma unroll
    for (int r = 0; r < K1_ROWS; ++r) s[r] = 0.f;

#pragma unroll
    for (int r = 0; r < K1_ROWS; ++r) {
#pragma unroll
        for (int jj = 0; jj < 16; ++jj) {
            const int j = (jj + dblk) & 15;      // runtime -> LDS ADDRESS only
            float4 xv = *reinterpret_cast<const float4*>(&xs[r][dblk * 64 + j * 4]);
            float4 b  = bw[jj];                  // compile-time register index
            s[r] = fmaf(xv.x, b.x, s[r]); s[r] = fmaf(xv.y, b.y, s[r]);
            s[r] = fmaf(xv.z, b.z, s[r]); s[r] = fmaf(xv.w, b.w, s[r]);
        }
    }

    // reduce over dblk within wave (4 groups of 16), then across 4 waves
#pragma unroll
    for (int r = 0; r < K1_ROWS; ++r) {
        float v = s[r];
        v += __shfl_xor(v, 16);
        v += __shfl_xor(v, 32);
        s[r] = v;
    }
    if (lane < 16) {
#pragma unroll
        for (int r = 0; r < K1_ROWS; ++r) red[wid][r][lane] = s[r];
    }
    __syncthreads();
    if (tid < K1_ROWS * 16) {
        const int r = tid >> 4, n2 = tid & 15;
        float v = red[0][r][n2] + red[1][r][n2] + red[2][r][n2] + red[3][r][n2];
        bx[(size_t)(row0 + r) * D_STATE + tid - r * 16 - n2 + n2] = v;  // = [(row0+r)*16 + n2]
    }
}

// ---------------------------------------------------------------------------
// K2: KbarT[delta][n] = (1/1024) * sum_d decay[d][n]^delta,  decay=exp(-exp(A))
// ---------------------------------------------------------------------------
__global__ __launch_bounds__(256) void k_kbar(const float* __restrict__ A_log,
                                              float* __restrict__ KbarT) {
    const int n = blockIdx.x;
    const int tid = threadIdx.x;
    const int lane = tid & 63, wid = tid >> 6;
    __shared__ float red[4];
    float p[4], dec[4];
#pragma unroll
    for (int j = 0; j < 4; ++j) {
        int d = tid * 4 + j;
        float a = A_log[d * D_STATE + n];
        dec[j] = expf(-expf(a));
        p[j] = 1.f;
    }
    for (int delta = 0; delta < WIN; ++delta) {
        float s = p[0] + p[1] + p[2] + p[3];
#pragma unroll
        for (int off = 32; off; off >>= 1) s += __shfl_xor(s, off);
        if (lane == 0) red[wid] = s;
        __syncthreads();
        if (tid == 0)
            KbarT[delta * D_STATE + n] = (red[0] + red[1] + red[2] + red[3]) * (1.0f / 1024.0f);
        __syncthreads();
#pragma unroll
        for (int j = 0; j < 4; ++j) p[j] *= dec[j];
    }
}

// ---------------------------------------------------------------------------
// K3 (fused FIR + output): per block of 8 rows:
//   hm[r][n] = sum_delta KbarT[delta][n] * bx[row-delta][n]   (threads 0..127)
//   y = hm @ C_w^T + D*x ; out = layernorm(y)*gamma + beta
// ---------------------------------------------------------------------------
#define K4_ROWS 8
__global__ __launch_bounds__(256) void k_out(const float* __restrict__ x,
                                             const float* __restrict__ bxg,
                                             const float* __restrict__ KbarT,
                                             const float* __restrict__ Cw,
                                             const float* __restrict__ Dp,
                                             const float* __restrict__ gamma,
                                             const float* __restrict__ beta,
                                             float* __restrict__ out) {
    const int tid = threadIdx.x;
    const int row0 = blockIdx.x * K4_ROWS;
    const int lane = tid & 63, wid = tid >> 6;
    __shared__ float kb[WIN * D_STATE];           // [delta][n]
    __shared__ float hm_s[K4_ROWS][D_STATE];
    __shared__ float red_s[4], red_q[4];

    // stage Kbar (4 KB)
    for (int i = tid; i < WIN * D_STATE; i += 256) kb[i] = KbarT[i];

    // preload C_w rows d = 4*tid..+3 (16 floats each) -> 64 VGPRs
    float4 cw[4][4];
#pragma unroll
    for (int j = 0; j < 4; ++j) {
        const float4* p = reinterpret_cast<const float4*>(Cw + (size_t)(tid * 4 + j) * D_STATE);
#pragma unroll
        for (int q = 0; q < 4; ++q) cw[j][q] = p[q];
    }
    const float4 Dv = reinterpret_cast<const float4*>(Dp)[tid];
    const float4 gv = reinterpret_cast<const float4*>(gamma)[tid];
    const float4 bv = reinterpret_cast<const float4*>(beta)[tid];
    __syncthreads();

    // FIR: threads 0..127 each own (r, n)
    if (tid < K4_ROWS * D_STATE) {
        const int r = tid >> 4, n = tid & 15;
        const int row = row0 + r;
        const int t = row & (SEQ - 1);
        const float* bp = bxg + (size_t)row * D_STATE + n;
        float acc = 0.f;
        if (t >= WIN - 1) {
#pragma unroll
            for (int delta = 0; delta < WIN; ++delta)
                acc = fmaf(kb[delta * D_STATE + n], bp[-(ptrdiff_t)delta * D_STATE], acc);
        } else {
            const int kw = t + 1;
            for (int delta = 0; delta < kw; ++delta)
                acc = fmaf(kb[delta * D_STATE + n], bp[-(ptrdiff_t)delta * D_STATE], acc);
        }
        hm_s[r][n] = acc;
    }
    __syncthreads();

    for (int r = 0; r < K4_ROWS; ++r) {
        const size_t row = row0 + r;
        const float4* hmp = reinterpret_cast<const float4*>(&hm_s[r][0]);
        float4 h0 = hmp[0], h1 = hmp[1], h2 = hmp[2], h3 = hmp[3]; // broadcast reads
        float4 xv = reinterpret_cast<const float4*>(x + row * 1024)[tid];

        float y[4];
#pragma unroll
        for (int j = 0; j < 4; ++j) {
            float a = 0.f;
            a = fmaf(h0.x, cw[j][0].x, a); a = fmaf(h0.y, cw[j][0].y, a);
            a = fmaf(h0.z, cw[j][0].z, a); a = fmaf(h0.w, cw[j][0].w, a);
            a = fmaf(h1.x, cw[j][1].x, a); a = fmaf(h1.y, cw[j][1].y, a);
            a = fmaf(h1.z, cw[j][1].z, a); a = fmaf(h1.w, cw[j][1].w, a);
            a = fmaf(h2.x, cw[j][2].x, a); a = fmaf(h2.y, cw[j][2].y, a);
            a = fmaf(h2.z, cw[j][2].z, a); a = fmaf(h2.w, cw[j][2].w, a);
            a = fmaf(h3.x, cw[j][3].x, a); a = fmaf(h3.y, cw[j][3].y, a);
            a = fmaf(h3.z, cw[j][3].z, a); a = fmaf(h3.w, cw[j][3].w, a);
            y[j] = a;
        }
        y[0] = fmaf(Dv.x, xv.x, y[0]);
        y[1] = fmaf(Dv.y, xv.y, y[1]);
        y[2] = fmaf(Dv.z, xv.z, y[2]);
        y[3] = fmaf(Dv.w, xv.w, y[3]);

        float s  = y[0] + y[1] + y[2] + y[3];
        float sq = y[0]*y[0] + y[1]*y[1] + y[2]*y[2] + y[3]*y[3];
#pragma unroll
        for (int off = 32; off; off >>= 1) {
            s  += __shfl_xor(s,  off);
            sq += __shfl_xor(sq, off);
        }
        if (lane == 0) { red_s[wid] = s; red_q[wid] = sq; }
        __syncthreads();
        float ssum = red_s[0] + red_s[1] + red_s[2] + red_s[3];
        float ssq  = red_q[0] + red_q[1] + red_q[2] + red_q[3];
        float mu   = ssum * (1.0f / 1024.0f);
        float var  = ssq * (1.0f / 1024.0f) - mu * mu;
        float inv  = rsqrtf(var + 1e-5f);
        float4 o;
        o.x = fmaf((y[0] - mu) * inv, gv.x, bv.x);
        o.y = fmaf((y[1] - mu) * inv, gv.y, bv.y);
        o.z = fmaf((y[2] - mu) * inv, gv.z, bv.z);
        o.w = fmaf((y[3] - mu) * inv, gv.w, bv.w);
        reinterpret_cast<float4*>(out + row * 1024)[tid] = o;
        __syncthreads();   // protect red_* before next row
    }
}

extern "C" void kernel_launch(void* const* d_in, const int* in_sizes, int n_in,
                              void* d_out, int out_size, void* d_ws, size_t ws_size,
                              hipStream_t stream) {
    (void)in_sizes; (void)n_in; (void)out_size; (void)ws_size;
    const float* x     = (const float*)d_in[0];
    const float* A_log = (const float*)d_in[1];
    const float* B_w   = (const float*)d_in[2];
    const float* C_w   = (const float*)d_in[3];
    const float* Dp    = (const float*)d_in[4];
    const float* gamma = (const float*)d_in[5];
    const float* beta  = (const float*)d_in[6];
    float* out = (float*)d_out;

    float* bx = (float*)d_ws;                       // ROWS*16 floats (512 KB)
    float* kb = bx + (size_t)ROWS * D_STATE;        // WIN*16 floats (4 KB)

    k_bx  <<<ROWS / K1_ROWS, 256, 0, stream>>>(x, B_w, bx);
    k_kbar<<<D_STATE,        256, 0, stream>>>(A_log, kb);
    k_out <<<ROWS / K4_ROWS, 256, 0, stream>>>(x, bx, kb, C_w, Dp, gamma, beta, out);
}